// Round 9
// baseline (172.873 us; speedup 1.0000x reference)
//
#include <hip/hip_runtime.h>
#include <hip/hip_fp16.h>

#define F_IN 48
#define F_HID 64
#define GSH 7            // nodes per bucket = 128
#define GSZ 128
#define MAXB 1024        // supports N <= 131072 (pack: src in 17 bits, g in 7)
#define CAPSH 12         // edges capacity per bucket = 4096 (avg 2048, +45 sigma)
#define CAP 4096
#define CHUNK 4096       // edges per passA block (16 per thread)

__device__ __forceinline__ bool detect64(const int* __restrict__ e) {
    return ((e[1] | e[3] | e[5] | e[7]) == 0);
}
__device__ __forceinline__ int load_src(const int* e, int i, int E, bool is64) {
    return e[is64 ? (long)2 * i : (long)i];
}
__device__ __forceinline__ int load_dst(const int* e, int i, int E, bool is64) {
    return e[is64 ? (long)2 * (E + i) : (long)(E + i)];
}
__device__ __forceinline__ float rdlane(float v, int l) {
    return __uint_as_float(__builtin_amdgcn_readlane(__float_as_uint(v), l));
}

// ---- pass A: chunk reservation; rank-capturing LDS histogram ----
__global__ __launch_bounds__(256) void passA(const int* __restrict__ e,
                                             int* __restrict__ bcnt,
                                             int* __restrict__ ebuf, int E, int B) {
    __shared__ int lcnt[MAXB], lbase[MAXB];
    bool is64 = detect64(e);
    bool vec = ((E & 3) == 0);
    int base = blockIdx.x * CHUNK;
    for (int t = threadIdx.x; t < B; t += 256) lcnt[t] = 0;
    __syncthreads();
    int pk[16], bk[16], rk[16];
#pragma unroll
    for (int g = 0; g < 4; ++g) {
        int i = base + (((g << 8) + (int)threadIdx.x) << 2);
        int r = g * 4;
        if (vec && i + 3 < E) {
            int4 s4, d4;
            if (is64) {
                const int4* p = (const int4*)(e + (size_t)2 * i);
                int4 a = p[0], bb = p[1];
                s4 = make_int4(a.x, a.z, bb.x, bb.z);
                const int4* q = (const int4*)(e + (size_t)2 * E + (size_t)2 * i);
                int4 c = q[0], dd = q[1];
                d4 = make_int4(c.x, c.z, dd.x, dd.z);
            } else {
                s4 = *(const int4*)(e + i);
                d4 = *(const int4*)(e + E + i);
            }
            int ss[4] = {s4.x, s4.y, s4.z, s4.w};
            int dv[4] = {d4.x, d4.y, d4.z, d4.w};
#pragma unroll
            for (int u = 0; u < 4; ++u) {
                pk[r + u] = ss[u] | ((dv[u] & (GSZ - 1)) << 17);
                bk[r + u] = dv[u] >> GSH;
                rk[r + u] = atomicAdd(&lcnt[bk[r + u]], 1);
            }
        } else {
#pragma unroll
            for (int u = 0; u < 4; ++u) {
                int ii = i + u;
                if (ii < E) {
                    int s = load_src(e, ii, E, is64);
                    int d = load_dst(e, ii, E, is64);
                    pk[r + u] = s | ((d & (GSZ - 1)) << 17);
                    bk[r + u] = d >> GSH;
                    rk[r + u] = atomicAdd(&lcnt[bk[r + u]], 1);
                } else {
                    bk[r + u] = -1;
                }
            }
        }
    }
    __syncthreads();
    for (int t = threadIdx.x; t < B; t += 256) {
        int c = lcnt[t];
        lbase[t] = c ? atomicAdd(&bcnt[t], c) : 0;
    }
    __syncthreads();
#pragma unroll
    for (int r = 0; r < 16; ++r) {
        if (bk[r] >= 0) {
            int pos = lbase[bk[r]] + rk[r];
            if (pos < CAP) ebuf[((size_t)bk[r] << CAPSH) + pos] = pk[r];
        }
    }
}

// ---- pass B: per-bucket rank-capture sort + vectorized y16 prep ----
__global__ __launch_bounds__(256) void passB(const int* __restrict__ ebuf,
                                             const int* __restrict__ bcnt,
                                             const float* __restrict__ x,
                                             int* __restrict__ rowStart,
                                             int* __restrict__ deg,
                                             float* __restrict__ dinv,
                                             int* __restrict__ srcSorted,
                                             __half* __restrict__ y, int N) {
    __shared__ int cnt[GSZ], inc[GSZ], exo[GSZ];
    __shared__ float ldinv[GSZ];
    int b = blockIdx.x, t = threadIdx.x;
    int m = min(bcnt[b], CAP);
    const int* eb = ebuf + ((size_t)b << CAPSH);
    if (t < GSZ) cnt[t] = 0;
    __syncthreads();
    int gk[16], sk[16], rk[16];
    int iters = (m + 255) >> 8;   // <= 16
    for (int it = 0; it < iters; ++it) {
        int i = t + (it << 8);
        if (i < m) {
            int pkv = eb[i];
            gk[it] = pkv >> 17;
            sk[it] = pkv & 0x1FFFF;
            rk[it] = atomicAdd(&cnt[gk[it]], 1);
        } else {
            gk[it] = -1;
        }
    }
    __syncthreads();
    int myc = (t < GSZ) ? cnt[t] : 0;
    if (t < GSZ) inc[t] = myc;
    __syncthreads();
    for (int o = 1; o < GSZ; o <<= 1) {
        int v = (t < GSZ && t >= o) ? inc[t - o] : 0;
        __syncthreads();
        if (t < GSZ) inc[t] += v;
        __syncthreads();
    }
    if (t < GSZ) {
        int ex = inc[t] - myc;
        exo[t] = ex;
        float di = rsqrtf((float)myc + 1.0f);
        ldinv[t] = di;
        int node = (b << GSH) + t;
        if (node < N) {
            rowStart[node] = (b << CAPSH) + ex;
            deg[node] = myc;
            dinv[node] = di;
        }
    }
    __syncthreads();
    int s0b = b << CAPSH;
    for (int it = 0; it < iters; ++it) {
        if (gk[it] >= 0)
            srcSorted[s0b + exo[gk[it]] + rk[it]] = sk[it];
    }
    int nodeBase = b << GSH;
    for (int q = t; q < GSZ * 16; q += 256) {
        int nl = q >> 4, k4 = (q & 15) << 2;
        int node = nodeBase + nl;
        if (node < N) {
            ushort4 hv;
            if (k4 < F_IN) {
                float di = ldinv[nl];
                float4 xv = *(const float4*)(x + (size_t)node * F_IN + k4);
                hv.x = __half_as_ushort(__float2half(di * xv.x));
                hv.y = __half_as_ushort(__float2half(di * xv.y));
                hv.z = __half_as_ushort(__float2half(di * xv.z));
                hv.w = __half_as_ushort(__float2half(di * xv.w));
            } else {
                hv.x = hv.y = hv.z = hv.w = 0;
            }
            *(ushort4*)((char*)y + ((size_t)node << 7) + ((size_t)k4 << 1)) = hv;
        }
    }
}

// ---- fused: 4 nodes/wave, 8B/lane gathers (4 edges per instruction),
// readlane GEMM epilogue ----
__global__ __launch_bounds__(256) void fused1(const __half* __restrict__ y,
                                              const float* __restrict__ W1,
                                              const float* __restrict__ b1,
                                              const float* __restrict__ W2,
                                              const float* __restrict__ dinv,
                                              const int* __restrict__ rowStart,
                                              const int* __restrict__ deg,
                                              const int* __restrict__ srcSorted,
                                              float* __restrict__ g2, int N) {
    const int lane = threadIdx.x & 63;
    const int sub = lane >> 4;       // which of 4 slots-in-a-quad this 16-lane group takes
    const int fl = lane & 15;        // 8-byte unit within a 128-B row
    const int base = blockIdx.x * 16 + (threadIdx.x >> 6) * 4;
    const char* yb = (const char*)y;
    const unsigned fb = (unsigned)fl << 3;

    int n0 = base, n1 = base + 1, n2 = base + 2, n3 = base + 3;
    int dn0 = (n0 < N) ? deg[n0] : -1;
    int dn1 = (n1 < N) ? deg[n1] : -1;
    int dn2_ = (n2 < N) ? deg[n2] : -1;
    int dn3 = (n3 < N) ? deg[n3] : -1;
    int rs0 = (n0 < N) ? rowStart[n0] : 0;
    int rs1 = (n1 < N) ? rowStart[n1] : 0;
    int rs2 = (n2 < N) ? rowStart[n2] : 0;
    int rs3 = (n3 < N) ? rowStart[n3] : 0;

    // slot map per lane: [0,dn)=edges, dn=self, rest=zero row N
    int idx0 = N, idx1 = N, idx2 = N, idx3 = N;
    if (lane < dn0) idx0 = srcSorted[rs0 + lane]; else if (lane == dn0) idx0 = n0;
    if (lane < dn1) idx1 = srcSorted[rs1 + lane]; else if (lane == dn1) idx1 = n1;
    if (lane < dn2_) idx2 = srcSorted[rs2 + lane]; else if (lane == dn2_) idx2 = n2;
    if (lane < dn3) idx3 = srcSorted[rs3 + lane]; else if (lane == dn3) idx3 = n3;

    // per-lane accumulators: 4 halves (features 4*fl .. 4*fl+3 of the 64-pad row)
    float a0x = 0, a0y = 0, a0z = 0, a0w = 0;
    float a1x = 0, a1y = 0, a1z = 0, a1w = 0;
    float a2x = 0, a2y = 0, a2z = 0, a2w = 0;
    float a3x = 0, a3y = 0, a3z = 0, a3w = 0;

    auto step = [&](int p) {
        int sA = 4 * p + sub;
        unsigned o0 = ((unsigned)__shfl(idx0, sA, 64) << 7) + fb;
        unsigned o1 = ((unsigned)__shfl(idx1, sA, 64) << 7) + fb;
        unsigned o2 = ((unsigned)__shfl(idx2, sA, 64) << 7) + fb;
        unsigned o3 = ((unsigned)__shfl(idx3, sA, 64) << 7) + fb;
        uint2 r0 = *(const uint2*)(yb + o0);
        uint2 r1 = *(const uint2*)(yb + o1);
        uint2 r2 = *(const uint2*)(yb + o2);
        uint2 r3 = *(const uint2*)(yb + o3);
        float2 l0 = __half22float2(*(const __half2*)&r0.x), h0v = __half22float2(*(const __half2*)&r0.y);
        float2 l1 = __half22float2(*(const __half2*)&r1.x), h1v = __half22float2(*(const __half2*)&r1.y);
        float2 l2 = __half22float2(*(const __half2*)&r2.x), h2v = __half22float2(*(const __half2*)&r2.y);
        float2 l3 = __half22float2(*(const __half2*)&r3.x), h3v = __half22float2(*(const __half2*)&r3.y);
        a0x += l0.x; a0y += l0.y; a0z += h0v.x; a0w += h0v.y;
        a1x += l1.x; a1y += l1.y; a1z += h1v.x; a1w += h1v.y;
        a2x += l2.x; a2y += l2.y; a2z += h2v.x; a2w += h2v.y;
        a3x += l3.x; a3y += l3.y; a3z += h3v.x; a3w += h3v.y;
    };
#pragma unroll
    for (int p = 0; p < 6; ++p) step(p);   // 24 slots; 24 gather instrs in flight
    int maxSlot = max(max(dn0, dn1), max(dn2_, dn3)) + 1;
    for (int p = 6; p < 16 && 4 * p < maxSlot; ++p) step(p);  // covers to 64
    if (maxSlot > 64) {  // astronomically rare
        for (int s = 64; s < maxSlot; ++s) {
            if (sub == 0) {  // lanes 0-15 cover one row
                if (s <= dn0) {
                    uint2 r = *(const uint2*)(yb + (((unsigned)((s < dn0) ? srcSorted[rs0 + s] : n0)) << 7) + fb);
                    float2 lo = __half22float2(*(const __half2*)&r.x), hi = __half22float2(*(const __half2*)&r.y);
                    a0x += lo.x; a0y += lo.y; a0z += hi.x; a0w += hi.y;
                }
                if (s <= dn1) {
                    uint2 r = *(const uint2*)(yb + (((unsigned)((s < dn1) ? srcSorted[rs1 + s] : n1)) << 7) + fb);
                    float2 lo = __half22float2(*(const __half2*)&r.x), hi = __half22float2(*(const __half2*)&r.y);
                    a1x += lo.x; a1y += lo.y; a1z += hi.x; a1w += hi.y;
                }
                if (s <= dn2_) {
                    uint2 r = *(const uint2*)(yb + (((unsigned)((s < dn2_) ? srcSorted[rs2 + s] : n2)) << 7) + fb);
                    float2 lo = __half22float2(*(const __half2*)&r.x), hi = __half22float2(*(const __half2*)&r.y);
                    a2x += lo.x; a2y += lo.y; a2z += hi.x; a2w += hi.y;
                }
                if (s <= dn3) {
                    uint2 r = *(const uint2*)(yb + (((unsigned)((s < dn3) ? srcSorted[rs3 + s] : n3)) << 7) + fb);
                    float2 lo = __half22float2(*(const __half2*)&r.x), hi = __half22float2(*(const __half2*)&r.y);
                    a3x += lo.x; a3y += lo.y; a3z += hi.x; a3w += hi.y;
                }
            }
        }
    }

    // reduce the 4 sub-groups (lanes l, l^16, l^32, l^48): 2 xor-shuffles
#pragma unroll
    for (int off = 16; off <= 32; off <<= 1) {
        a0x += __shfl_xor(a0x, off, 64); a0y += __shfl_xor(a0y, off, 64);
        a0z += __shfl_xor(a0z, off, 64); a0w += __shfl_xor(a0w, off, 64);
        a1x += __shfl_xor(a1x, off, 64); a1y += __shfl_xor(a1y, off, 64);
        a1z += __shfl_xor(a1z, off, 64); a1w += __shfl_xor(a1w, off, 64);
        a2x += __shfl_xor(a2x, off, 64); a2y += __shfl_xor(a2y, off, 64);
        a2z += __shfl_xor(a2z, off, 64); a2w += __shfl_xor(a2w, off, 64);
        a3x += __shfl_xor(a3x, off, 64); a3y += __shfl_xor(a3y, off, 64);
        a3z += __shfl_xor(a3z, off, 64); a3w += __shfl_xor(a3w, off, 64);
    }
    float di0 = (n0 < N) ? dinv[n0] : 0.0f;
    float di1 = (n1 < N) ? dinv[n1] : 0.0f;
    float di2 = (n2 < N) ? dinv[n2] : 0.0f;
    float di3 = (n3 < N) ? dinv[n3] : 0.0f;
    a0x *= di0; a0y *= di0; a0z *= di0; a0w *= di0;
    a1x *= di1; a1y *= di1; a1z *= di1; a1w *= di1;
    a2x *= di2; a2y *= di2; a2z *= di2; a2w *= di2;
    a3x *= di3; a3y *= di3; a3z *= di3; a3w *= di3;

    // lane q in [0,12) holds v[4q..4q+4) in (x,y,z,w); GEMM via readlane
    float h0 = b1[lane], h1 = h0, h2 = h0, h3 = h0;
#pragma unroll
    for (int q = 0; q < 12; ++q) {
        float w0 = W1[(4 * q + 0) * F_HID + lane];
        float w1 = W1[(4 * q + 1) * F_HID + lane];
        float w2_ = W1[(4 * q + 2) * F_HID + lane];
        float w3 = W1[(4 * q + 3) * F_HID + lane];
        h0 = fmaf(rdlane(a0x, q), w0, h0); h0 = fmaf(rdlane(a0y, q), w1, h0);
        h0 = fmaf(rdlane(a0z, q), w2_, h0); h0 = fmaf(rdlane(a0w, q), w3, h0);
        h1 = fmaf(rdlane(a1x, q), w0, h1); h1 = fmaf(rdlane(a1y, q), w1, h1);
        h1 = fmaf(rdlane(a1z, q), w2_, h1); h1 = fmaf(rdlane(a1w, q), w3, h1);
        h2 = fmaf(rdlane(a2x, q), w0, h2); h2 = fmaf(rdlane(a2y, q), w1, h2);
        h2 = fmaf(rdlane(a2z, q), w2_, h2); h2 = fmaf(rdlane(a2w, q), w3, h2);
        h3 = fmaf(rdlane(a3x, q), w0, h3); h3 = fmaf(rdlane(a3y, q), w1, h3);
        h3 = fmaf(rdlane(a3z, q), w2_, h3); h3 = fmaf(rdlane(a3w, q), w3, h3);
    }
    h0 = fmaxf(h0, 0.0f); h1 = fmaxf(h1, 0.0f);
    h2 = fmaxf(h2, 0.0f); h3 = fmaxf(h3, 0.0f);

    float2 w2 = ((const float2*)W2)[lane];
    float t00 = h0 * w2.x, t01 = h0 * w2.y;
    float t10 = h1 * w2.x, t11 = h1 * w2.y;
    float t20 = h2 * w2.x, t21 = h2 * w2.y;
    float t30 = h3 * w2.x, t31 = h3 * w2.y;
#pragma unroll
    for (int off = 32; off > 0; off >>= 1) {
        t00 += __shfl_down(t00, off, 64); t01 += __shfl_down(t01, off, 64);
        t10 += __shfl_down(t10, off, 64); t11 += __shfl_down(t11, off, 64);
        t20 += __shfl_down(t20, off, 64); t21 += __shfl_down(t21, off, 64);
        t30 += __shfl_down(t30, off, 64); t31 += __shfl_down(t31, off, 64);
    }
    if (lane == 0) {
        float2* g2v = (float2*)g2;
        if (n0 < N) g2v[n0] = make_float2(di0 * t00, di0 * t01);
        if (n1 < N) g2v[n1] = make_float2(di1 * t10, di1 * t11);
        if (n2 < N) g2v[n2] = make_float2(di2 * t20, di2 * t21);
        if (n3 < N) g2v[n3] = make_float2(di3 * t30, di3 * t31);
    }
}

// ---- layer-2 aggregation: 16 lanes per node, 32-bit offsets ----
__global__ __launch_bounds__(256) void agg2(const int* __restrict__ rowStart,
                                            const int* __restrict__ deg,
                                            const int* __restrict__ srcSorted,
                                            const float* __restrict__ g2,
                                            const float* __restrict__ dinv,
                                            const float* __restrict__ b2,
                                            float* __restrict__ out, int N) {
    int gid = blockIdx.x * 256 + threadIdx.x;
    int node = gid >> 4, l16 = gid & 15;
    if (node >= N) return;
    const char* gb = (const char*)g2;
    int rs = rowStart[node], dn = deg[node];
    float a0 = 0.0f, a1 = 0.0f;
    for (int j = l16; j < dn; j += 16) {
        unsigned o = (unsigned)srcSorted[rs + j] << 3;
        float2 v = *(const float2*)(gb + o);
        a0 += v.x;
        a1 += v.y;
    }
#pragma unroll
    for (int m = 1; m < 16; m <<= 1) {
        a0 += __shfl_xor(a0, m, 64);
        a1 += __shfl_xor(a1, m, 64);
    }
    if (l16 == 0) {
        float2 self = *(const float2*)(gb + ((unsigned)node << 3));
        float di = dinv[node];
        out[2 * node + 0] = di * (a0 + self.x) + b2[0];
        out[2 * node + 1] = di * (a1 + self.y) + b2[1];
    }
}

extern "C" void kernel_launch(void* const* d_in, const int* in_sizes, int n_in,
                              void* d_out, int out_size, void* d_ws, size_t ws_size,
                              hipStream_t stream) {
    const float* x  = (const float*)d_in[0];
    const int* eidx = (const int*)d_in[1];
    const float* W1 = (const float*)d_in[2];
    const float* b1 = (const float*)d_in[3];
    const float* W2 = (const float*)d_in[4];
    const float* b2 = (const float*)d_in[5];
    float* out = (float*)d_out;

    int N = in_sizes[0] / F_IN;   // 100000
    int E = in_sizes[1] / 2;      // 1600000
    int B = (N + GSZ - 1) >> GSH; // 782 buckets (<= MAXB)

    char* ws = (char*)d_ws;
    __half* y16       = (__half*)ws;   ws += (size_t)(N + 1) * 64 * 2;  // +zero row
    int*    bcnt      = (int*)ws;      ws += MAXB * 4;
    int*    deg       = (int*)ws;      ws += (size_t)N * 4;
    int*    rowStart  = (int*)ws;      ws += (size_t)N * 4;
    float*  dinv      = (float*)ws;    ws += (size_t)N * 4;
    float*  g2        = (float*)ws;    ws += (size_t)N * 2 * 4;
    ws = (char*)(((size_t)ws + 255) & ~(size_t)255);
    int*    ebuf      = (int*)ws;      ws += (size_t)MAXB * CAP * 4;
    int*    srcSorted = (int*)ws;      ws += (size_t)MAXB * CAP * 4;

    hipMemsetAsync(y16 + (size_t)N * 64, 0, 128 + MAXB * 4, stream);

    passA<<<(E + CHUNK - 1) / CHUNK, 256, 0, stream>>>(eidx, bcnt, ebuf, E, B);
    passB<<<B, 256, 0, stream>>>(ebuf, bcnt, x, rowStart, deg, dinv, srcSorted,
                                 y16, N);
    fused1<<<(N + 15) / 16, 256, 0, stream>>>(y16, W1, b1, W2, dinv, rowStart, deg,
                                              srcSorted, g2, N);
    agg2<<<(N * 16 + 255) / 256, 256, 0, stream>>>(rowStart, deg, srcSorted, g2,
                                                   dinv, b2, out, N);
}